// Round 13
// baseline (17427.219 us; speedup 1.0000x reference)
//
#include <hip/hip_runtime.h>
#include <hip/hip_bf16.h>
#include <math.h>

#define T_STEPS 2048
#define N_MOD   64
#define N_HID   256
#define N_INP   128

// Relaxed-ONLY agent-scope (sc1) ops — no acquire/release anywhere in the
// persistent kernel (R1/R7: agent-acquire emits cache invalidates, ~25us).
// Ordering: wave-level s_waitcnt vmcnt(0) ACKs the sc1 hy stores at the LLC
// coherence point before the flag store issues (same wave -> program order).
__device__ __forceinline__ void AG_STF(float* p, float v) {
  __hip_atomic_store(p, v, __ATOMIC_RELAXED, __HIP_MEMORY_SCOPE_AGENT);
}
__device__ __forceinline__ void AG_STU(unsigned* p, unsigned v) {
  __hip_atomic_store(p, v, __ATOMIC_RELAXED, __HIP_MEMORY_SCOPE_AGENT);
}
__device__ __forceinline__ unsigned AG_LDU(const unsigned* p) {
  return __hip_atomic_load(p, __ATOMIC_RELAXED, __HIP_MEMORY_SCOPE_AGENT);
}

// --------------------------------------------------------------------------
__global__ __launch_bounds__(512) void init_kernel(
    const float* __restrict__ init, float* __restrict__ out_states)
{
  const int idx = blockIdx.x * 512 + threadIdx.x;
  out_states[idx] = init[idx];
}

// --------------------------------------------------------------------------
// Pre-pass: xpre[t,n,h] -> fb_seq region of d_out (overwritten with fb later;
// read-before-write per thread; re-established every launch/replay).
// --------------------------------------------------------------------------
__global__ __launch_bounds__(256, 2) void xpre_kernel(
    const float* __restrict__ x, const float* __restrict__ x2h,
    float* __restrict__ out)
{
  __shared__ float xl[64 * N_INP];
  const int tb = blockIdx.x;
  const int n  = blockIdx.y;
  const int t  = threadIdx.x;

  const float4* xs  = (const float4*)(x + (size_t)tb * 64 * N_INP);
  float4*       xld = (float4*)xl;
  for (int k = t; k < 64 * N_INP / 4; k += 256) xld[k] = xs[k];

  float w[N_INP];
  const float* wrow = x2h + ((size_t)n * N_HID + t) * N_INP;
#pragma unroll
  for (int j = 0; j < N_INP; j += 4) {
    const float4 a = *(const float4*)(wrow + j);
    w[j] = a.x; w[j+1] = a.y; w[j+2] = a.z; w[j+3] = a.w;
  }
  __syncthreads();

  for (int tt = 0; tt < 64; ++tt) {
    float a0=0.f, a1=0.f, a2=0.f, a3=0.f;
#pragma unroll
    for (int j = 0; j < N_INP; j += 4) {
      const float4 h4 = *(const float4*)&xl[tt * N_INP + j];
      a0 = fmaf(w[j],   h4.x, a0);
      a1 = fmaf(w[j+1], h4.y, a1);
      a2 = fmaf(w[j+2], h4.z, a2);
      a3 = fmaf(w[j+3], h4.w, a3);
    }
    out[((size_t)(tb*64 + tt) * N_MOD + n) * N_HID + t] = (a0+a1)+(a2+a3);
  }
}

// --------------------------------------------------------------------------
// FALLBACK (R6-proven): one kernel per timestep, if coop launch is rejected.
// --------------------------------------------------------------------------
__global__ __launch_bounds__(256) void step_kernel(
    int k, const float* __restrict__ wm, const float* __restrict__ conn,
    const float* __restrict__ h2h, const float* __restrict__ bias,
    float* __restrict__ out_states, float* __restrict__ out_fb)
{
  const int b  = blockIdx.x;
  const int m  = b >> 2;
  const int q  = b & 3;
  const int i  = threadIdx.x;
  const int ro = i & 63;
  const int jq = i >> 6;

  __shared__ float hym[N_HID];
  __shared__ float u[N_HID];
  __shared__ float redr[256];
  __shared__ float redf[256];

  const float* hyk = out_states + (size_t)k * N_MOD * 512;

  hym[i] = hyk[(size_t)m * 512 + i];
  {
    float ua=0.f, ub=0.f, uc=0.f, ud=0.f;
#pragma unroll
    for (int mm = 0; mm < N_MOD; mm += 4) {
      ua = fmaf(conn[m * N_MOD + mm + 0], hyk[(size_t)(mm + 0) * 512 + i], ua);
      ub = fmaf(conn[m * N_MOD + mm + 1], hyk[(size_t)(mm + 1) * 512 + i], ub);
      uc = fmaf(conn[m * N_MOD + mm + 2], hyk[(size_t)(mm + 2) * 512 + i], uc);
      ud = fmaf(conn[m * N_MOD + mm + 3], hyk[(size_t)(mm + 3) * 512 + i], ud);
    }
    u[i] = (ua + ub) + (uc + ud);
  }
  float xq = 0.f, hyv = 0.f, hzv = 0.f, bv = 0.f;
  if (i < 64) {
    const int hu = q * 64 + i;
    xq  = out_fb[((size_t)k * N_MOD + m) * N_HID + hu];
    hyv = hyk[(size_t)m * 512 + hu];
    hzv = hyk[(size_t)m * 512 + 256 + hu];
    bv  = bias[m * N_HID + hu];
  }
  __syncthreads();

  {
    const int h = q * 64 + ro;
    const float* hrow = h2h + ((size_t)m * N_HID + h) * N_HID + jq * 64;
    const float* wrow = wm  + (size_t)h * N_HID + jq * 64;
    float r0=0.f, r1=0.f, r2=0.f, r3=0.f;
    float f0=0.f, f1=0.f, f2=0.f, f3=0.f;
#pragma unroll
    for (int j = 0; j < 64; j += 4) {
      const float4 a  = *(const float4*)(hrow + j);
      const float4 w4 = *(const float4*)(wrow + j);
      const float4 hv = *(const float4*)(&hym[jq * 64 + j]);
      const float4 uv = *(const float4*)(&u[jq * 64 + j]);
      r0 = fmaf(a.x, hv.x, r0);  f0 = fmaf(w4.x, uv.x, f0);
      r1 = fmaf(a.y, hv.y, r1);  f1 = fmaf(w4.y, uv.y, f1);
      r2 = fmaf(a.z, hv.z, r2);  f2 = fmaf(w4.z, uv.z, f2);
      r3 = fmaf(a.w, hv.w, r3);  f3 = fmaf(w4.w, uv.w, f3);
    }
    redr[i] = (r0 + r1) + (r2 + r3);
    redf[i] = (f0 + f1) + (f2 + f3);
  }
  __syncthreads();

  if (i < 64) {
    const int hu = q * 64 + i;
    const float r  = (redr[i] + redr[i + 64]) + (redr[i + 128] + redr[i + 192]);
    const float fb = (k == 0) ? 0.f
                   : (redf[i] + redf[i + 64]) + (redf[i + 128] + redf[i + 192]);
    const float pre = xq + r + bv + fb;
    const float th  = tanhf(pre);
    const float hzn = hzv + 0.01f * (th - hyv - hzv);
    const float hyn = hyv + 0.01f * hzn;
    const size_t ob = ((size_t)(k + 1) * N_MOD + m) * 512;
    out_states[ob + hu]       = hyn;
    out_states[ob + 256 + hu] = hzn;
    out_fb[((size_t)k * N_MOD + m) * N_HID + hu] = fb;
  }
}

// --------------------------------------------------------------------------
// Persistent kernel: 256 WGs x 256 thr (~67KB LDS -> 2 WG/CU, launch-safe).
// WG (m=b>>2, q=b&3) owns rows [q*64,+64). Thread i: ro=i&63, jq=i>>6.
// Wave 0 (i<64) = ALL update rows -> publish is one coalesced sc1 store
// + WAVE-LEVEL vmcnt(0) + lane0 flag (no all-wave drain).
// Wave 1 (64<=i<128) polls the 256 flags CONCURRENTLY with wave 0's
// update+publish; one __syncthreads joins both, then all waves gather.
//
// Iter k: [w0: reduce redr/redf -> update -> sc1 publish hy_{k+1} ->
//          vmcnt(0) -> flag=k+1 -> hz/fb stores + xpre prefetch]
//         [w1: poll 256 flags >= k+1]   (concurrent)
//   B1;  all: wm reg-prefetch (16xfloat4, hides under gather),
//             hym + u-gather (plain cached loads, L2-dedup'd);
//   B2;  all: dual matvec (wA LDS-swizzled, wm regs, padded vecs) -> red*;
//   B0'.
// fb_0 = 0 exactly: u_l zeroed -> pre-loop matvec gives redf == 0.
// Replay-safe: flags memset per launch; gather addresses fresh per step.
// --------------------------------------------------------------------------
__global__ __launch_bounds__(256) void archnet_persist(
    const float* __restrict__ init, const float* __restrict__ wm,
    const float* __restrict__ conn, const float* __restrict__ h2h,
    const float* __restrict__ bias,
    float* __restrict__ out_states, float* __restrict__ out_fb,
    unsigned* __restrict__ flags)
{
  __shared__ float wA[64 * 256];      // 64 KB h2h quarter, swizzled
  __shared__ float hym_l[4 * 68];     // padded hy_k[m] (68: bank-spread)
  __shared__ float u_l[4 * 68];       // padded u
  __shared__ float redr[256];
  __shared__ float redf[256];
  __shared__ float connrow[N_MOD];

  const int b  = blockIdx.x;          // 0..255
  const int m  = b >> 2;
  const int q  = b & 3;
  const int i  = threadIdx.x;         // 0..255
  const int ro = i & 63;
  const int jq = i >> 6;
  const int hu = q * 64 + ro;         // global row (w0 update row when i<64)
  const int pi = jq * 68 + ro;        // padded index for column i

  if (i < N_MOD) connrow[i] = conn[m * N_MOD + i];
  u_l[pi] = 0.f;                      // k=0: redf becomes exact zeros
  hym_l[pi] = init[(size_t)m * 512 + i];

  // ---- stage h2h quarter -> LDS, swizzled: group g at row rr -> g^(rr&7) ----
  for (int idx = i; idx < 64 * 64; idx += 256) {
    const int rr = idx >> 6, g = idx & 63;
    const float4 a = *(const float4*)(h2h + ((size_t)m * N_HID + q * 64 + rr) * N_HID + g * 4);
    *(float4*)&wA[rr * 256 + (g ^ (rr & 7)) * 4] = a;
  }

  // ---- wave-0 per-row persistent state ----
  float hyv = 0.f, hzv = 0.f, bv = 0.f, xq = 0.f;
  if (i < 64) {
    hyv = init[(size_t)m * 512 + hu];
    hzv = init[(size_t)m * 512 + 256 + hu];
    bv  = bias[m * N_HID + hu];
    xq  = out_fb[(size_t)m * N_HID + hu];             // xpre_0
  }
  __syncthreads();

  // ---- pre-loop matvec: step-0 partials (redf = 0 since u = 0) ----
  {
    const float* wrow = wm + (size_t)hu * N_HID + jq * 64;
    float r0=0.f, r1=0.f, r2=0.f, r3=0.f;
    float f0=0.f, f1=0.f, f2=0.f, f3=0.f;
#pragma unroll
    for (int j = 0; j < 16; ++j) {
      const int gs = ((jq * 16 + j) ^ (ro & 7)) * 4;
      const float4 a  = *(const float4*)&wA[ro * 256 + gs];
      const float4 w4 = *(const float4*)(wrow + j * 4);
      const float4 hv = *(const float4*)&hym_l[jq * 68 + j * 4];
      const float4 uv = *(const float4*)&u_l[jq * 68 + j * 4];
      r0 = fmaf(a.x, hv.x, r0);  f0 = fmaf(w4.x, uv.x, f0);
      r1 = fmaf(a.y, hv.y, r1);  f1 = fmaf(w4.y, uv.y, f1);
      r2 = fmaf(a.z, hv.z, r2);  f2 = fmaf(w4.z, uv.z, f2);
      r3 = fmaf(a.w, hv.w, r3);  f3 = fmaf(w4.w, uv.w, f3);
    }
    redr[i] = (r0 + r1) + (r2 + r3);
    redf[i] = (f0 + f1) + (f2 + f3);
  }
  __syncthreads();

  for (int k = 0; k < T_STEPS; ++k) {
    // ---- phase 1 (concurrent wave roles) ----
    if (i < 64) {
      // w0: reduce, update, publish, flag, outputs
      const float r  = (redr[i] + redr[i + 64]) + (redr[i + 128] + redr[i + 192]);
      const float fb = (redf[i] + redf[i + 64]) + (redf[i + 128] + redf[i + 192]);
      const float pre = xq + r + bv + fb;
      const float th  = tanhf(pre);
      hzv = hzv + 0.01f * (th - hyv - hzv);     // GAMMA=EPS=1, DT=0.01
      hyv = hyv + 0.01f * hzv;

      AG_STF(out_states + (size_t)(k + 1) * (N_MOD * 512) + (size_t)m * 512 + hu,
             hyv);                               // coalesced sc1 publish
      asm volatile("s_waitcnt vmcnt(0)" ::: "memory");  // wave-level ACK
      if (i == 0) AG_STU(&flags[b], (unsigned)(k + 1));

      const size_t ob = ((size_t)(k + 1) * N_MOD + m) * 512;
      out_states[ob + 256 + hu] = hzv;
      out_fb[((size_t)k * N_MOD + m) * N_HID + hu] = fb;   // overwrite xpre[k]
      if (k + 1 < T_STEPS)
        xq = out_fb[((size_t)(k + 1) * N_MOD + m) * N_HID + hu];
    } else if (i < 128 && k + 1 < T_STEPS) {
      // w1: poll all 256 flags >= k+1 (overlaps w0's update+publish)
      const unsigned kk = (unsigned)(k + 1);
      const int fb4 = (i - 64) * 4;
      for (;;) {
        const unsigned f0 = AG_LDU(&flags[fb4 + 0]);
        const unsigned f1 = AG_LDU(&flags[fb4 + 1]);
        const unsigned f2 = AG_LDU(&flags[fb4 + 2]);
        const unsigned f3 = AG_LDU(&flags[fb4 + 3]);
        if (!__any(f0 < kk || f1 < kk || f2 < kk || f3 < kk)) break;
        __builtin_amdgcn_s_sleep(1);
      }
    }
    __syncthreads();                  // B1: publish + poll complete

    if (k + 1 < T_STEPS) {
      // ---- wm transient reg-prefetch (latency hides under gather) ----
      float4 wreg[16];
      {
        const float* wrow = wm + (size_t)hu * N_HID + jq * 64;
#pragma unroll
        for (int j = 0; j < 16; ++j) wreg[j] = ((const float4*)wrow)[j];
      }

      // ---- gather hy_{k+1}: plain cached loads (L2-dedup'd) ----
      const float* hyk1 = out_states + (size_t)(k + 1) * (N_MOD * 512);
      hym_l[pi] = hyk1[(size_t)m * 512 + i];
      {
        float ua=0.f, ub=0.f, uc=0.f, ud=0.f;
#pragma unroll
        for (int mm = 0; mm < N_MOD; mm += 4) {
          ua = fmaf(connrow[mm+0], hyk1[(size_t)(mm+0) * 512 + i], ua);
          ub = fmaf(connrow[mm+1], hyk1[(size_t)(mm+1) * 512 + i], ub);
          uc = fmaf(connrow[mm+2], hyk1[(size_t)(mm+2) * 512 + i], uc);
          ud = fmaf(connrow[mm+3], hyk1[(size_t)(mm+3) * 512 + i], ud);
        }
        u_l[pi] = (ua + ub) + (uc + ud);
      }
      __syncthreads();                // B2: hym + u visible (+ wreg complete)

      // ---- dual quarter-row matvecs (wA LDS, wm regs, padded vecs) ----
      {
        float r0=0.f, r1=0.f, r2=0.f, r3=0.f;
        float f0=0.f, f1=0.f, f2=0.f, f3=0.f;
#pragma unroll
        for (int j = 0; j < 16; ++j) {
          const int gs = ((jq * 16 + j) ^ (ro & 7)) * 4;
          const float4 a  = *(const float4*)&wA[ro * 256 + gs];
          const float4 hv = *(const float4*)&hym_l[jq * 68 + j * 4];
          const float4 uv = *(const float4*)&u_l[jq * 68 + j * 4];
          r0 = fmaf(a.x, hv.x, r0);  f0 = fmaf(wreg[j].x, uv.x, f0);
          r1 = fmaf(a.y, hv.y, r1);  f1 = fmaf(wreg[j].y, uv.y, f1);
          r2 = fmaf(a.z, hv.z, r2);  f2 = fmaf(wreg[j].z, uv.z, f2);
          r3 = fmaf(a.w, hv.w, r3);  f3 = fmaf(wreg[j].w, uv.w, f3);
        }
        redr[i] = (r0 + r1) + (r2 + r3);
        redf[i] = (f0 + f1) + (f2 + f3);
      }
      __syncthreads();                // B0': partials ready for next w0 reduce
    }
  }
}

// --------------------------------------------------------------------------
extern "C" void kernel_launch(void* const* d_in, const int* in_sizes, int n_in,
                              void* d_out, int out_size, void* d_ws, size_t ws_size,
                              hipStream_t stream) {
  const float* x    = (const float*)d_in[0];   // (2048,128)
  const float* init = (const float*)d_in[1];   // (64,2,256)
  const float* wmw  = (const float*)d_in[2];   // (256,256)
  const float* conn = (const float*)d_in[3];   // (64,64)
  const float* x2h  = (const float*)d_in[4];   // (64,256,128)
  const float* h2h  = (const float*)d_in[5];   // (64,256,256)
  const float* bias = (const float*)d_in[6];   // (64,256)

  float* out_states = (float*)d_out;                                        // (2049,64,2,256)
  float* out_fb     = out_states + (size_t)(T_STEPS+1) * N_MOD * 2 * N_HID; // (2048,64,256)

  unsigned* flags = (unsigned*)d_ws;           // 256 monotone per-WG counters
  hipMemsetAsync(d_ws, 0, 1024, stream);

  init_kernel<<<64, 512, 0, stream>>>(init, out_states);
  xpre_kernel<<<dim3(T_STEPS/64, N_MOD), dim3(256), 0, stream>>>(x, x2h, out_fb);

  void* args[] = {
    (void*)&init, (void*)&wmw, (void*)&conn, (void*)&h2h, (void*)&bias,
    (void*)&out_states, (void*)&out_fb, (void*)&flags
  };
  hipError_t err = hipLaunchCooperativeKernel((void*)archnet_persist,
                                              dim3(256), dim3(256),
                                              args, 0, stream);
  if (err != hipSuccess) {
    for (int k = 0; k < T_STEPS; ++k)
      step_kernel<<<256, 256, 0, stream>>>(k, wmw, conn, h2h, bias,
                                           out_states, out_fb);
  }
}

// Round 14
// 14794.531 us; speedup vs baseline: 1.1780x; 1.1780x over previous
//
#include <hip/hip_runtime.h>
#include <hip/hip_bf16.h>
#include <math.h>

#define T_STEPS 2048
#define N_MOD   64
#define N_HID   256
#define N_INP   128

// Relaxed-ONLY agent-scope (sc1) ops — no acquire/release anywhere in the
// persistent kernel (R1/R7: agent-acquire emits cache invalidates, ~25us).
// Ordering: per-WAVE s_waitcnt vmcnt(0) ACKs that wave's sc1 publish stores
// at the LLC coherence point before the wave's sub-flag store issues.
__device__ __forceinline__ void AG_STF(float* p, float v) {
  __hip_atomic_store(p, v, __ATOMIC_RELAXED, __HIP_MEMORY_SCOPE_AGENT);
}
__device__ __forceinline__ void AG_STU(unsigned* p, unsigned v) {
  __hip_atomic_store(p, v, __ATOMIC_RELAXED, __HIP_MEMORY_SCOPE_AGENT);
}
__device__ __forceinline__ unsigned AG_LDU(const unsigned* p) {
  return __hip_atomic_load(p, __ATOMIC_RELAXED, __HIP_MEMORY_SCOPE_AGENT);
}

// --------------------------------------------------------------------------
__global__ __launch_bounds__(512) void init_kernel(
    const float* __restrict__ init, float* __restrict__ out_states)
{
  const int idx = blockIdx.x * 512 + threadIdx.x;
  out_states[idx] = init[idx];
}

// --------------------------------------------------------------------------
// Pre-pass: xpre[t,n,h] -> fb_seq region of d_out (overwritten with fb later;
// read-before-write per thread; re-established every launch/replay).
// --------------------------------------------------------------------------
__global__ __launch_bounds__(256, 2) void xpre_kernel(
    const float* __restrict__ x, const float* __restrict__ x2h,
    float* __restrict__ out)
{
  __shared__ float xl[64 * N_INP];
  const int tb = blockIdx.x;
  const int n  = blockIdx.y;
  const int t  = threadIdx.x;

  const float4* xs  = (const float4*)(x + (size_t)tb * 64 * N_INP);
  float4*       xld = (float4*)xl;
  for (int k = t; k < 64 * N_INP / 4; k += 256) xld[k] = xs[k];

  float w[N_INP];
  const float* wrow = x2h + ((size_t)n * N_HID + t) * N_INP;
#pragma unroll
  for (int j = 0; j < N_INP; j += 4) {
    const float4 a = *(const float4*)(wrow + j);
    w[j] = a.x; w[j+1] = a.y; w[j+2] = a.z; w[j+3] = a.w;
  }
  __syncthreads();

  for (int tt = 0; tt < 64; ++tt) {
    float a0=0.f, a1=0.f, a2=0.f, a3=0.f;
#pragma unroll
    for (int j = 0; j < N_INP; j += 4) {
      const float4 h4 = *(const float4*)&xl[tt * N_INP + j];
      a0 = fmaf(w[j],   h4.x, a0);
      a1 = fmaf(w[j+1], h4.y, a1);
      a2 = fmaf(w[j+2], h4.z, a2);
      a3 = fmaf(w[j+3], h4.w, a3);
    }
    out[((size_t)(tb*64 + tt) * N_MOD + n) * N_HID + t] = (a0+a1)+(a2+a3);
  }
}

// --------------------------------------------------------------------------
// FALLBACK (R6-proven): one kernel per timestep, if coop launch is rejected.
// --------------------------------------------------------------------------
__global__ __launch_bounds__(256) void step_kernel(
    int k, const float* __restrict__ wm, const float* __restrict__ conn,
    const float* __restrict__ h2h, const float* __restrict__ bias,
    float* __restrict__ out_states, float* __restrict__ out_fb)
{
  const int b  = blockIdx.x;
  const int m  = b >> 2;
  const int q  = b & 3;
  const int i  = threadIdx.x;
  const int ro = i & 63;
  const int jq = i >> 6;

  __shared__ float hym[N_HID];
  __shared__ float u[N_HID];
  __shared__ float redr[256];
  __shared__ float redf[256];

  const float* hyk = out_states + (size_t)k * N_MOD * 512;

  hym[i] = hyk[(size_t)m * 512 + i];
  {
    float ua=0.f, ub=0.f, uc=0.f, ud=0.f;
#pragma unroll
    for (int mm = 0; mm < N_MOD; mm += 4) {
      ua = fmaf(conn[m * N_MOD + mm + 0], hyk[(size_t)(mm + 0) * 512 + i], ua);
      ub = fmaf(conn[m * N_MOD + mm + 1], hyk[(size_t)(mm + 1) * 512 + i], ub);
      uc = fmaf(conn[m * N_MOD + mm + 2], hyk[(size_t)(mm + 2) * 512 + i], uc);
      ud = fmaf(conn[m * N_MOD + mm + 3], hyk[(size_t)(mm + 3) * 512 + i], ud);
    }
    u[i] = (ua + ub) + (uc + ud);
  }
  float xq = 0.f, hyv = 0.f, hzv = 0.f, bv = 0.f;
  if (i < 64) {
    const int hu = q * 64 + i;
    xq  = out_fb[((size_t)k * N_MOD + m) * N_HID + hu];
    hyv = hyk[(size_t)m * 512 + hu];
    hzv = hyk[(size_t)m * 512 + 256 + hu];
    bv  = bias[m * N_HID + hu];
  }
  __syncthreads();

  {
    const int h = q * 64 + ro;
    const float* hrow = h2h + ((size_t)m * N_HID + h) * N_HID + jq * 64;
    const float* wrow = wm  + (size_t)h * N_HID + jq * 64;
    float r0=0.f, r1=0.f, r2=0.f, r3=0.f;
    float f0=0.f, f1=0.f, f2=0.f, f3=0.f;
#pragma unroll
    for (int j = 0; j < 64; j += 4) {
      const float4 a  = *(const float4*)(hrow + j);
      const float4 w4 = *(const float4*)(wrow + j);
      const float4 hv = *(const float4*)(&hym[jq * 64 + j]);
      const float4 uv = *(const float4*)(&u[jq * 64 + j]);
      r0 = fmaf(a.x, hv.x, r0);  f0 = fmaf(w4.x, uv.x, f0);
      r1 = fmaf(a.y, hv.y, r1);  f1 = fmaf(w4.y, uv.y, f1);
      r2 = fmaf(a.z, hv.z, r2);  f2 = fmaf(w4.z, uv.z, f2);
      r3 = fmaf(a.w, hv.w, r3);  f3 = fmaf(w4.w, uv.w, f3);
    }
    redr[i] = (r0 + r1) + (r2 + r3);
    redf[i] = (f0 + f1) + (f2 + f3);
  }
  __syncthreads();

  if (i < 64) {
    const int hu = q * 64 + i;
    const float r  = (redr[i] + redr[i + 64]) + (redr[i + 128] + redr[i + 192]);
    const float fb = (k == 0) ? 0.f
                   : (redf[i] + redf[i + 64]) + (redf[i + 128] + redf[i + 192]);
    const float pre = xq + r + bv + fb;
    const float th  = tanhf(pre);
    const float hzn = hzv + 0.01f * (th - hyv - hzv);
    const float hyn = hyv + 0.01f * hzn;
    const size_t ob = ((size_t)(k + 1) * N_MOD + m) * 512;
    out_states[ob + hu]       = hyn;
    out_states[ob + 256 + hu] = hzn;
    out_fb[((size_t)k * N_MOD + m) * N_HID + hu] = fb;
  }
}

// --------------------------------------------------------------------------
// Persistent kernel (R12 structure + per-wave sub-flags + local own-rows):
// 256 WGs x 256 thr (~68KB LDS -> 2 WG/CU, launch-safe). WG (m=b>>2, q=b&3)
// owns rows [q*64,+64). Thread i: r=i>>2, c4=i&3; global row hq=q*64+r.
//
// Per step k:
//  (a) poll: thread i polls the 4 sub-flags of WG i (>= k), s_sleep backoff.
//      SYNC-A.
//  (b) gather step-k hy (plain cached loads, L2-dedup'd): hym_l[k&1]
//      (sibling rows only — own 64 rows were written locally at k-1) and
//      u_l (conn-weighted column sums). SYNC-B.
//  (c) dual quarter-row matvecs (wA LDS-swizzled + wm inline from hot L2,
//      padded vectors) -> quad-shfl reduce (intra-wave, no barrier).
//  (d) c4==0: tanh Euler update; sc1 publish hy_{k+1} -> out_states[k+1];
//      local hym_l[(k+1)&1] own-row write (parity-safe vs (c) readers).
//      ALL: per-wave s_waitcnt vmcnt(0); lane 0 of each wave: sub-flag=k+1.
//      c4==0: hz/fb stores + xpre prefetch (fire-and-forget, after flag).
// 2 barriers/step (was 3): the all-wave drain barrier is gone — each wave's
// flag goes out as soon as ITS stores ACK at the LLC.
// Replay-safe: flags memset each launch; gather addresses fresh per step;
// replays rewrite identical values so warm-cache reads are benign.
// --------------------------------------------------------------------------
__global__ __launch_bounds__(256) void archnet_persist(
    const float* __restrict__ init, const float* __restrict__ wm,
    const float* __restrict__ conn, const float* __restrict__ h2h,
    const float* __restrict__ bias,
    float* __restrict__ out_states, float* __restrict__ out_fb,
    unsigned* __restrict__ flags)
{
  __shared__ float wA[64 * 256];      // 64 KB h2h quarter, swizzled
  __shared__ float hym_l[2][4 * 68];  // parity-buffered padded hy_k[m]
  __shared__ float u_l[4 * 68];       // padded u
  __shared__ float connrow[N_MOD];

  const int b  = blockIdx.x;          // 0..255
  const int m  = b >> 2;
  const int q  = b & 3;
  const int i  = threadIdx.x;         // 0..255
  const int r  = i >> 2;              // local row 0..63
  const int c4 = i & 3;               // 64-col chunk
  const int hq = q * 64 + r;          // global row
  const int pi = (i >> 6) * 68 + (i & 63);   // padded index for column i

  if (i < N_MOD) connrow[i] = conn[m * N_MOD + i];
  u_l[pi] = 0.f;                      // k=0: fb term reads zeros
  hym_l[0][pi] = init[(size_t)m * 512 + i];

  // ---- stage h2h quarter -> LDS, swizzled: group g at row rr -> g^(rr&7) ----
  for (int idx = i; idx < 64 * 64; idx += 256) {   // 64 rows x 64 f4-groups
    const int rr = idx >> 6, g = idx & 63;
    const float4 a = *(const float4*)(h2h + ((size_t)m * N_HID + q * 64 + rr) * N_HID + g * 4);
    *(float4*)&wA[rr * 256 + (g ^ (rr & 7)) * 4] = a;
  }

  // ---- per-row persistent state (c4==0 lanes) ----
  float hyv = 0.f, hzv = 0.f, bv = 0.f, xq = 0.f;
  if (c4 == 0) {
    hyv = init[(size_t)m * 512 + hq];
    hzv = init[(size_t)m * 512 + 256 + hq];
    bv  = bias[m * N_HID + hq];
    xq  = out_fb[(size_t)m * N_HID + hq];             // xpre_0
  }

  const float* wrow = wm + (size_t)hq * N_HID + c4 * 64;  // L2-hot stream

  for (int k = 0; k < T_STEPS; ++k) {
    const int pr = k & 1, pw = (k + 1) & 1;

    // ---- (a) poll: thread i checks WG i's 4 per-wave sub-flags ----
    if (k > 0) {
      const unsigned kk = (unsigned)k;
      const unsigned* f4 = &flags[i * 4];
      for (;;) {
        const unsigned f0 = AG_LDU(&f4[0]);
        const unsigned f1 = AG_LDU(&f4[1]);
        const unsigned f2 = AG_LDU(&f4[2]);
        const unsigned f3 = AG_LDU(&f4[3]);
        if (f0 >= kk && f1 >= kk && f2 >= kk && f3 >= kk) break;
        __builtin_amdgcn_s_sleep(1);
      }
    }
    __syncthreads();                  // SYNC-A: all data of step k published

    // ---- (b) gather step-k hy: plain cached loads (L2-dedup'd) ----
    const float* hyk = out_states + (size_t)k * (N_MOD * 512);
    if (k > 0) {
      if ((i >> 6) != q)              // own 64 rows already written locally
        hym_l[pr][pi] = hyk[(size_t)m * 512 + i];
      float ua=0.f, ub=0.f, uc=0.f, ud=0.f;
#pragma unroll
      for (int mm = 0; mm < N_MOD; mm += 4) {
        ua = fmaf(connrow[mm+0], hyk[(size_t)(mm+0) * 512 + i], ua);
        ub = fmaf(connrow[mm+1], hyk[(size_t)(mm+1) * 512 + i], ub);
        uc = fmaf(connrow[mm+2], hyk[(size_t)(mm+2) * 512 + i], uc);
        ud = fmaf(connrow[mm+3], hyk[(size_t)(mm+3) * 512 + i], ud);
      }
      u_l[pi] = (ua + ub) + (uc + ud);
    }
    __syncthreads();                  // SYNC-B: hym + u visible

    // ---- (c) dual quarter-row matvecs + quad-shfl reduce ----
    float rsum, fsum;
    {
      float r0=0.f, r1=0.f, r2=0.f, r3=0.f;
      float f0=0.f, f1=0.f, f2=0.f, f3=0.f;
#pragma unroll
      for (int j = 0; j < 16; ++j) {
        const int gs = ((c4 * 16 + j) ^ (r & 7)) * 4;
        const float4 a  = *(const float4*)&wA[r * 256 + gs];
        const float4 w4 = *(const float4*)(wrow + j * 4);
        const float4 hv = *(const float4*)&hym_l[pr][c4 * 68 + j * 4];
        const float4 uv = *(const float4*)&u_l[c4 * 68 + j * 4];
        r0 = fmaf(a.x, hv.x, r0);  f0 = fmaf(w4.x, uv.x, f0);
        r1 = fmaf(a.y, hv.y, r1);  f1 = fmaf(w4.y, uv.y, f1);
        r2 = fmaf(a.z, hv.z, r2);  f2 = fmaf(w4.z, uv.z, f2);
        r3 = fmaf(a.w, hv.w, r3);  f3 = fmaf(w4.w, uv.w, f3);
      }
      rsum = (r0 + r1) + (r2 + r3);
      fsum = (f0 + f1) + (f2 + f3);
      rsum += __shfl_xor(rsum, 1); rsum += __shfl_xor(rsum, 2);
      fsum += __shfl_xor(fsum, 1); fsum += __shfl_xor(fsum, 2);
    }

    // ---- (d) update + publish + per-wave flag ----
    float fbv = 0.f;
    if (c4 == 0) {
      fbv = (k == 0) ? 0.f : fsum;
      const float pre = xq + rsum + bv + fbv;
      const float th  = tanhf(pre);
      hzv = hzv + 0.01f * (th - hyv - hzv);     // GAMMA=EPS=1, DT=0.01
      hyv = hyv + 0.01f * hzv;
      AG_STF(out_states + (size_t)(k + 1) * (N_MOD * 512) + (size_t)m * 512 + hq,
             hyv);                              // sc1 -> LLC, cross-XCD visible
      hym_l[pw][q * 68 + r] = hyv;              // own row, next-parity buffer
    }
    asm volatile("s_waitcnt vmcnt(0)" ::: "memory");  // per-WAVE store ACK
    if ((i & 63) == 0)
      AG_STU(&flags[b * 4 + (i >> 6)], (unsigned)(k + 1));  // wave sub-flag

    // ---- outputs + xpre prefetch (fire-and-forget, after flag) ----
    if (c4 == 0) {
      const size_t ob = ((size_t)(k + 1) * N_MOD + m) * 512;
      out_states[ob + 256 + hq] = hzv;
      out_fb[((size_t)k * N_MOD + m) * N_HID + hq] = fbv;  // overwrite xpre[k]
      if (k + 1 < T_STEPS)
        xq = out_fb[((size_t)(k + 1) * N_MOD + m) * N_HID + hq];
    }
  }
}

// --------------------------------------------------------------------------
extern "C" void kernel_launch(void* const* d_in, const int* in_sizes, int n_in,
                              void* d_out, int out_size, void* d_ws, size_t ws_size,
                              hipStream_t stream) {
  const float* x    = (const float*)d_in[0];   // (2048,128)
  const float* init = (const float*)d_in[1];   // (64,2,256)
  const float* wmw  = (const float*)d_in[2];   // (256,256)
  const float* conn = (const float*)d_in[3];   // (64,64)
  const float* x2h  = (const float*)d_in[4];   // (64,256,128)
  const float* h2h  = (const float*)d_in[5];   // (64,256,256)
  const float* bias = (const float*)d_in[6];   // (64,256)

  float* out_states = (float*)d_out;                                        // (2049,64,2,256)
  float* out_fb     = out_states + (size_t)(T_STEPS+1) * N_MOD * 2 * N_HID; // (2048,64,256)

  unsigned* flags = (unsigned*)d_ws;           // 1024 per-wave sub-flags
  hipMemsetAsync(d_ws, 0, 4096, stream);

  init_kernel<<<64, 512, 0, stream>>>(init, out_states);
  xpre_kernel<<<dim3(T_STEPS/64, N_MOD), dim3(256), 0, stream>>>(x, x2h, out_fb);

  void* args[] = {
    (void*)&init, (void*)&wmw, (void*)&conn, (void*)&h2h, (void*)&bias,
    (void*)&out_states, (void*)&out_fb, (void*)&flags
  };
  hipError_t err = hipLaunchCooperativeKernel((void*)archnet_persist,
                                              dim3(256), dim3(256),
                                              args, 0, stream);
  if (err != hipSuccess) {
    for (int k = 0; k < T_STEPS; ++k)
      step_kernel<<<256, 256, 0, stream>>>(k, wmw, conn, h2h, bias,
                                           out_states, out_fb);
  }
}

// Round 15
// 10801.219 us; speedup vs baseline: 1.6134x; 1.3697x over previous
//
#include <hip/hip_runtime.h>
#include <hip/hip_bf16.h>
#include <math.h>

#define T_STEPS 2048
#define N_MOD   64
#define N_HID   256
#define N_INP   128

// Relaxed-ONLY agent-scope (sc1) ops — no acquire/release anywhere in the
// persistent kernel (R1/R7: agent-acquire emits cache invalidates, ~25us;
// R7 acq_rel barrier ≈ 25us). Ordering: each wave's s_waitcnt vmcnt(0)
// (implicit in __syncthreads) ACKs sc1 stores at the LLC coherence point
// before the flag store is issued.
__device__ __forceinline__ void AG_STF(float* p, float v) {
  __hip_atomic_store(p, v, __ATOMIC_RELAXED, __HIP_MEMORY_SCOPE_AGENT);
}
__device__ __forceinline__ void AG_STU(unsigned* p, unsigned v) {
  __hip_atomic_store(p, v, __ATOMIC_RELAXED, __HIP_MEMORY_SCOPE_AGENT);
}
__device__ __forceinline__ unsigned AG_LDU(const unsigned* p) {
  return __hip_atomic_load(p, __ATOMIC_RELAXED, __HIP_MEMORY_SCOPE_AGENT);
}

// --------------------------------------------------------------------------
// init: states_seq[0] = initial_states
// --------------------------------------------------------------------------
__global__ __launch_bounds__(512) void init_kernel(
    const float* __restrict__ init, float* __restrict__ out_states)
{
  const int idx = blockIdx.x * 512 + threadIdx.x;   // 64*512 = 32768 elems
  out_states[idx] = init[idx];
}

// --------------------------------------------------------------------------
// Pre-pass: xpre[t,n,h] = sum_i x2h[n,h,i] * x[t,i]  -> fb_seq region of d_out.
// Step kernels read xpre[t] then overwrite it with fb[t] (same thread,
// read-before-write; re-established every launch/replay).
// --------------------------------------------------------------------------
__global__ __launch_bounds__(256, 2) void xpre_kernel(
    const float* __restrict__ x, const float* __restrict__ x2h,
    float* __restrict__ out)
{
  __shared__ float xl[64 * N_INP];
  const int tb = blockIdx.x;
  const int n  = blockIdx.y;
  const int t  = threadIdx.x;

  const float4* xs  = (const float4*)(x + (size_t)tb * 64 * N_INP);
  float4*       xld = (float4*)xl;
  for (int k = t; k < 64 * N_INP / 4; k += 256) xld[k] = xs[k];

  float w[N_INP];
  const float* wrow = x2h + ((size_t)n * N_HID + t) * N_INP;
#pragma unroll
  for (int j = 0; j < N_INP; j += 4) {
    const float4 a = *(const float4*)(wrow + j);
    w[j] = a.x; w[j+1] = a.y; w[j+2] = a.z; w[j+3] = a.w;
  }
  __syncthreads();

  for (int tt = 0; tt < 64; ++tt) {
    float a0=0.f, a1=0.f, a2=0.f, a3=0.f;
#pragma unroll
    for (int j = 0; j < N_INP; j += 4) {
      const float4 h4 = *(const float4*)&xl[tt * N_INP + j];
      a0 = fmaf(w[j],   h4.x, a0);
      a1 = fmaf(w[j+1], h4.y, a1);
      a2 = fmaf(w[j+2], h4.z, a2);
      a3 = fmaf(w[j+3], h4.w, a3);
    }
    out[((size_t)(tb*64 + tt) * N_MOD + n) * N_HID + t] = (a0+a1)+(a2+a3);
  }
}

// --------------------------------------------------------------------------
// FALLBACK (R6-proven, 16.4 ms): one kernel per timestep. Used only if the
// cooperative launch is rejected (R8/R10 failure mode).
// --------------------------------------------------------------------------
__global__ __launch_bounds__(256) void step_kernel(
    int k, const float* __restrict__ wm, const float* __restrict__ conn,
    const float* __restrict__ h2h, const float* __restrict__ bias,
    float* __restrict__ out_states, float* __restrict__ out_fb)
{
  const int b  = blockIdx.x;
  const int m  = b >> 2;
  const int q  = b & 3;
  const int i  = threadIdx.x;
  const int ro = i & 63;
  const int jq = i >> 6;

  __shared__ float hym[N_HID];
  __shared__ float u[N_HID];
  __shared__ float redr[256];
  __shared__ float redf[256];

  const float* hyk = out_states + (size_t)k * N_MOD * 512;

  hym[i] = hyk[(size_t)m * 512 + i];
  {
    float ua=0.f, ub=0.f, uc=0.f, ud=0.f;
#pragma unroll
    for (int mm = 0; mm < N_MOD; mm += 4) {
      ua = fmaf(conn[m * N_MOD + mm + 0], hyk[(size_t)(mm + 0) * 512 + i], ua);
      ub = fmaf(conn[m * N_MOD + mm + 1], hyk[(size_t)(mm + 1) * 512 + i], ub);
      uc = fmaf(conn[m * N_MOD + mm + 2], hyk[(size_t)(mm + 2) * 512 + i], uc);
      ud = fmaf(conn[m * N_MOD + mm + 3], hyk[(size_t)(mm + 3) * 512 + i], ud);
    }
    u[i] = (ua + ub) + (uc + ud);
  }
  float xq = 0.f, hyv = 0.f, hzv = 0.f, bv = 0.f;
  if (i < 64) {
    const int hu = q * 64 + i;
    xq  = out_fb[((size_t)k * N_MOD + m) * N_HID + hu];
    hyv = hyk[(size_t)m * 512 + hu];
    hzv = hyk[(size_t)m * 512 + 256 + hu];
    bv  = bias[m * N_HID + hu];
  }
  __syncthreads();

  {
    const int h = q * 64 + ro;
    const float* hrow = h2h + ((size_t)m * N_HID + h) * N_HID + jq * 64;
    const float* wrow = wm  + (size_t)h * N_HID + jq * 64;
    float r0=0.f, r1=0.f, r2=0.f, r3=0.f;
    float f0=0.f, f1=0.f, f2=0.f, f3=0.f;
#pragma unroll
    for (int j = 0; j < 64; j += 4) {
      const float4 a  = *(const float4*)(hrow + j);
      const float4 w4 = *(const float4*)(wrow + j);
      const float4 hv = *(const float4*)(&hym[jq * 64 + j]);
      const float4 uv = *(const float4*)(&u[jq * 64 + j]);
      r0 = fmaf(a.x, hv.x, r0);  f0 = fmaf(w4.x, uv.x, f0);
      r1 = fmaf(a.y, hv.y, r1);  f1 = fmaf(w4.y, uv.y, f1);
      r2 = fmaf(a.z, hv.z, r2);  f2 = fmaf(w4.z, uv.z, f2);
      r3 = fmaf(a.w, hv.w, r3);  f3 = fmaf(w4.w, uv.w, f3);
    }
    redr[i] = (r0 + r1) + (r2 + r3);
    redf[i] = (f0 + f1) + (f2 + f3);
  }
  __syncthreads();

  if (i < 64) {
    const int hu = q * 64 + i;
    const float r  = (redr[i] + redr[i + 64]) + (redr[i + 128] + redr[i + 192]);
    const float fb = (k == 0) ? 0.f
                   : (redf[i] + redf[i + 64]) + (redf[i + 128] + redf[i + 192]);
    const float pre = xq + r + bv + fb;
    const float th  = tanhf(pre);
    const float hzn = hzv + 0.01f * (th - hyv - hzv);
    const float hyn = hyv + 0.01f * hzn;
    const size_t ob = ((size_t)(k + 1) * N_MOD + m) * 512;
    out_states[ob + hu]       = hyn;
    out_states[ob + 256 + hu] = hzn;
    out_fb[((size_t)k * N_MOD + m) * N_HID + hu] = fb;
  }
}

// --------------------------------------------------------------------------
// Persistent stepping kernel (R12 — best known: 9.95 ms, 4.86 us/step):
// 256 WGs x 256 thr (~67KB LDS -> 2 WG/CU -> coop capacity check passes).
// WG (m=b>>2, q=b&3) owns rows [q*64,+64) of module m. Thread i: row r=i>>2,
// chunk c4=i&3; global row hq=q*64+r.
//
// u-formulation: fb[m] = wm @ u[m], u[m,j] = sum_mm conn[m,mm]*hy_k[mm,j].
//
// Exchange = out_states itself (written once, sc1). Unique address per step
// -> consumers use PLAIN CACHED loads (L2-dedup across the XCD's 32 WGs;
// R11's per-element tagged sc1 gather was LLC-BW-bound at 33 MB/step).
//
// Sync: flags[256] monotone per-WG step counters (sc1). Producer: sc1 hy
// stores -> __syncthreads (each wave drains vmcnt -> stores ACKed at LLC;
// ALSO keeps waves phase-locked — R14's per-wave flags de-synced waves and
// regressed 48% with replay variance) -> one sc1 flag store. Consumer:
// wave-0 lanes poll 4 flags each (relaxed sc1 + s_sleep + ballot).
//
// LDS: h2h quarter (64KB, XOR-swizzled g^=row&7). hym/u padded to 68-float
// chunk stride (four c4 chunks on four distinct bank groups, float4-aligned)
// — fixed R11's 1.2e9 bank-conflict cycles down to 4e8 (residual is the
// structural 64-lane b128 row-read pigeonhole).
// wm streams inline from L2 (256KB chip-shared, hot after step 1).
// --------------------------------------------------------------------------
__global__ __launch_bounds__(256) void archnet_persist(
    const float* __restrict__ init, const float* __restrict__ wm,
    const float* __restrict__ conn, const float* __restrict__ h2h,
    const float* __restrict__ bias,
    float* __restrict__ out_states, float* __restrict__ out_fb,
    unsigned* __restrict__ flags)
{
  __shared__ float wA[64 * 256];      // 64 KB h2h quarter, swizzled
  __shared__ float hym_l[4 * 68];     // padded hy_k[m]
  __shared__ float u_l[4 * 68];       // padded u
  __shared__ float connrow[N_MOD];

  const int b  = blockIdx.x;          // 0..255
  const int m  = b >> 2;
  const int q  = b & 3;
  const int i  = threadIdx.x;         // 0..255
  const int r  = i >> 2;              // local row 0..63
  const int c4 = i & 3;               // 64-col chunk
  const int hq = q * 64 + r;          // global row
  const int pi = (i >> 6) * 68 + (i & 63);   // padded index for h-column i

  if (i < N_MOD) connrow[i] = conn[m * N_MOD + i];
  u_l[pi] = 0.f;                      // k=0: fb reads zeros

  // ---- stage h2h quarter -> LDS, swizzled ----
  for (int idx = i; idx < 64 * 64; idx += 256) {   // 64 rows x 64 f4-groups
    const int rr = idx >> 6, g = idx & 63;
    const float4 a = *(const float4*)(h2h + ((size_t)m * N_HID + q * 64 + rr) * N_HID + g * 4);
    *(float4*)&wA[rr * 256 + (g ^ (rr & 7)) * 4] = a;
  }

  // ---- per-row persistent state (c4==0 lanes) ----
  float hyv = 0.f, hzv = 0.f, bv = 0.f, xq = 0.f;
  if (c4 == 0) {
    hyv = init[(size_t)m * 512 + hq];
    hzv = init[(size_t)m * 512 + 256 + hq];
    bv  = bias[m * N_HID + hq];
    xq  = out_fb[(size_t)m * N_HID + hq];             // xpre_0
  }

  const float* wrow = wm + (size_t)hq * N_HID + c4 * 64;  // L2-resident

  for (int k = 0; k < T_STEPS; ++k) {
    // ---- (a) poll: all 256 producer flags >= k ----
    if (k > 0 && i < 64) {
      const unsigned kk = (unsigned)k;
      for (;;) {
        const unsigned f0 = AG_LDU(&flags[i * 4 + 0]);
        const unsigned f1 = AG_LDU(&flags[i * 4 + 1]);
        const unsigned f2 = AG_LDU(&flags[i * 4 + 2]);
        const unsigned f3 = AG_LDU(&flags[i * 4 + 3]);
        if (!__any(f0 < kk || f1 < kk || f2 < kk || f3 < kk)) break;
        __builtin_amdgcn_s_sleep(1);
      }
    }
    __syncthreads();                  // poll done; also orders LDS reuse

    // ---- (b) hym + u-gather: plain cached loads (L2-dedup'd) ----
    const float* hyk = out_states + (size_t)k * (N_MOD * 512);
    hym_l[pi] = hyk[(size_t)m * 512 + i];
    if (k > 0) {
      float ua=0.f, ub=0.f, uc=0.f, ud=0.f;
#pragma unroll
      for (int mm = 0; mm < N_MOD; mm += 4) {
        ua = fmaf(connrow[mm+0], hyk[(size_t)(mm+0) * 512 + i], ua);
        ub = fmaf(connrow[mm+1], hyk[(size_t)(mm+1) * 512 + i], ub);
        uc = fmaf(connrow[mm+2], hyk[(size_t)(mm+2) * 512 + i], uc);
        ud = fmaf(connrow[mm+3], hyk[(size_t)(mm+3) * 512 + i], ud);
      }
      u_l[pi] = (ua + ub) + (uc + ud);
    }
    __syncthreads();                  // hym + u visible

    // ---- dual quarter-row matvecs (wA LDS-swizzled, wm L2, vecs padded) ----
    float rsum, fsum;
    {
      float r0=0.f, r1=0.f, r2=0.f, r3=0.f;
      float f0=0.f, f1=0.f, f2=0.f, f3=0.f;
#pragma unroll
      for (int j = 0; j < 16; ++j) {
        const int gs = ((c4 * 16 + j) ^ (r & 7)) * 4;
        const float4 a  = *(const float4*)&wA[r * 256 + gs];
        const float4 w4 = *(const float4*)(wrow + j * 4);
        const float4 hv = *(const float4*)&hym_l[c4 * 68 + j * 4];
        const float4 uv = *(const float4*)&u_l[c4 * 68 + j * 4];
        r0 = fmaf(a.x, hv.x, r0);  f0 = fmaf(w4.x, uv.x, f0);
        r1 = fmaf(a.y, hv.y, r1);  f1 = fmaf(w4.y, uv.y, f1);
        r2 = fmaf(a.z, hv.z, r2);  f2 = fmaf(w4.z, uv.z, f2);
        r3 = fmaf(a.w, hv.w, r3);  f3 = fmaf(w4.w, uv.w, f3);
      }
      rsum = (r0 + r1) + (r2 + r3);
      fsum = (f0 + f1) + (f2 + f3);
      rsum += __shfl_xor(rsum, 1); rsum += __shfl_xor(rsum, 2);
      fsum += __shfl_xor(fsum, 1); fsum += __shfl_xor(fsum, 2);
    }

    // ---- (c) update + sc1 publish (only hy before the drain barrier) ----
    float fbv = 0.f;
    if (c4 == 0) {
      fbv = (k == 0) ? 0.f : fsum;
      const float pre = xq + rsum + bv + fbv;
      const float th  = tanhf(pre);
      hzv = hzv + 0.01f * (th - hyv - hzv);     // GAMMA=EPS=1, DT=0.01
      hyv = hyv + 0.01f * hzv;
      AG_STF(out_states + (size_t)(k + 1) * (N_MOD * 512) + (size_t)m * 512 + hq,
             hyv);                              // sc1 -> LLC, cross-XCD visible
    }
    __syncthreads();   // every wave drains vmcnt(0): hy stores ACKed at LLC
    if (i == 0) AG_STU(&flags[b], (unsigned)(k + 1));

    // ---- plain output stores + xpre prefetch (drain at NEXT step's poll) ----
    if (c4 == 0) {
      const size_t ob = ((size_t)(k + 1) * N_MOD + m) * 512;
      out_states[ob + 256 + hq] = hzv;
      out_fb[((size_t)k * N_MOD + m) * N_HID + hq] = fbv;  // overwrite xpre[k]
      if (k + 1 < T_STEPS)
        xq = out_fb[((size_t)(k + 1) * N_MOD + m) * N_HID + hq];
    }
  }
}

// --------------------------------------------------------------------------
extern "C" void kernel_launch(void* const* d_in, const int* in_sizes, int n_in,
                              void* d_out, int out_size, void* d_ws, size_t ws_size,
                              hipStream_t stream) {
  const float* x    = (const float*)d_in[0];   // (2048,128)
  const float* init = (const float*)d_in[1];   // (64,2,256)
  const float* wmw  = (const float*)d_in[2];   // (256,256)
  const float* conn = (const float*)d_in[3];   // (64,64)
  const float* x2h  = (const float*)d_in[4];   // (64,256,128)
  const float* h2h  = (const float*)d_in[5];   // (64,256,256)
  const float* bias = (const float*)d_in[6];   // (64,256)

  float* out_states = (float*)d_out;                                        // (2049,64,2,256)
  float* out_fb     = out_states + (size_t)(T_STEPS+1) * N_MOD * 2 * N_HID; // (2048,64,256)

  // workspace: flags[256] monotone per-WG counters, memset each launch.
  unsigned* flags = (unsigned*)d_ws;
  hipMemsetAsync(d_ws, 0, 1024, stream);

  init_kernel<<<64, 512, 0, stream>>>(init, out_states);
  xpre_kernel<<<dim3(T_STEPS/64, N_MOD), dim3(256), 0, stream>>>(x, x2h, out_fb);

  void* args[] = {
    (void*)&init, (void*)&wmw, (void*)&conn, (void*)&h2h, (void*)&bias,
    (void*)&out_states, (void*)&out_fb, (void*)&flags
  };
  hipError_t err = hipLaunchCooperativeKernel((void*)archnet_persist,
                                              dim3(256), dim3(256),
                                              args, 0, stream);
  if (err != hipSuccess) {
    // Fallback: kernel-per-step (R6-proven). Same math, same outputs.
    for (int k = 0; k < T_STEPS; ++k)
      step_kernel<<<256, 256, 0, stream>>>(k, wmw, conn, h2h, bias,
                                           out_states, out_fb);
  }
}